// Round 3
// baseline (232.386 us; speedup 1.0000x reference)
//
#include <hip/hip_runtime.h>
#include <hip/hip_fp16.h>
#include <cstddef>

// AffinityPropagate: per-pixel normalized 3x3 stencil, 24 steps.
// R8: thread unit reshaped 1x8 -> 2cols x 4rows (still 8 px/thread) so ALL
// LDS window traffic is vector: 12x ds_read_b64 (compiler pairs adjacent
// float2 loads -> ds_read2_b64) + 4x ds_write2_b32 per step instead of
// 30 b32 reads + 8 b32 writes. Per-CU LDS-pipe model said R6/R7 sat at
// ~60-65% LDS-pipe busy (38 wave-wide b32 ops x 5.8cy x 8 waves x 12 steps
// x 6 blocks/CU ~= 127K of 200K wall cycles); this roughly halves it.
// Bank math: each 32-lane phase reads 64 contiguous dwords (2/bank = free);
// writes are stride-2 dwords (2/bank = free). No shuffles, no guard rows
// (window rows 4rg..4rg+5 within staged 0..65). Single step per barrier
// (R7's 2-step fusion regressed: its shfl = ds_bpermute = LDS-pipe ops).
// Dead-wave skip kept. Weights stay packed half2 (fma_mix consumes halves).
//
// Tap order: w0=NW w1=N w2=NE w3=W [center] w4=E w5=SW w6=S w7=SE
//
// Ring/frontier: staged halo 13 (66x66), weight halo 12 (64x64 = staged rows/
// cols 1..64, rewritten every step). Valid staged rings after step s: [s,65-s];
// after 12 steps rows/cols 12..53 valid; output tile is 13..52. Out-of-image
// px have all-zero weights -> stay exactly 0 = zero padding.

#define HIMG 480
#define WIMG 640
#define HW   (HIMG * WIMG)
#define BN   8

#define TILE   40
#define TSTEPS 12
#define IH     13                // staged halo
#define WHL    12                // weight halo
#define SW     66                // staged rows/cols
#define PITCH  68                // LDS row pitch (floats), mult of 4
#define NT     512

#define WS_FRAME_B  ((size_t)BN * HW * 4)            // 9,830,400
#define WS_WA_B     ((size_t)BN * HW * 16)           // 39,321,600
#define WS_WC_B     ((size_t)BN * HW * 4)            // 9,830,400
#define WS_NEED     (WS_FRAME_B + WS_WA_B + WS_WC_B) // 58,982,400

// MODE: 0 = normalize in-kernel + store interior weights to wA/wC
//       1 = load packed weights from wA/wC
//       2 = normalize in-kernel, no store (fallback when ws too small)
template <int MODE>
__global__ __launch_bounds__(NT, 4) void affprop12(
    const float* __restrict__ aff,
    __half2* __restrict__ wA,
    float* __restrict__ wC,
    const float* __restrict__ src,
    float* __restrict__ dst)
{
    __shared__ float fA[SW * PITCH];
    __shared__ float fB[SW * PITCH];

    const int tid = threadIdx.x;
    const int ox  = blockIdx.x * TILE;
    const int oy  = blockIdx.y * TILE;
    const int b   = blockIdx.z;

    const float* __restrict__ sb = src + (size_t)b * HW;
    float*       __restrict__ db = dst + (size_t)b * HW;

    // ---- stage input region [oy-13, oy+53) x [ox-13, ox+53), 0 outside image
    for (int i = tid; i < SW * SW; i += NT) {
        int r  = i / SW;
        int c  = i - r * SW;
        int gy = oy - IH + r;
        int gx = ox - IH + c;
        float v = 0.f;
        if ((unsigned)gy < (unsigned)HIMG && (unsigned)gx < (unsigned)WIMG)
            v = sb[gy * WIMG + gx];
        fA[r * PITCH + c] = v;
    }
    // ---- zero-fill buffer B (deterministic stale rings)
    for (int i = tid; i < SW * PITCH / 4; i += NT)
        *(float4*)&fB[4 * i] = make_float4(0.f, 0.f, 0.f, 0.f);

    // ---- per-thread: 2 weight cols x 4 weight rows
    const int cu = tid & 31;          // col unit: weight cols 2cu, 2cu+1
    const int rg = tid >> 5;          // row group 0..15: weight rows 4rg..4rg+3
    const int w  = tid >> 6;          // wave id: weight rows 8w..8w+7

    __half2 wv[4][2][4];  // [row i][col k][tap pair (01)(23)(45)(67)]
    float   wcc[4][2];    // center weights (f32)

    #pragma unroll
    for (int i = 0; i < 4; ++i) {
        #pragma unroll
        for (int k = 0; k < 2; ++k) {
            const int gy = oy - WHL + 4 * rg + i;
            const int gx = ox - WHL + 2 * cu + k;
            const bool in = (unsigned)gy < (unsigned)HIMG && (unsigned)gx < (unsigned)WIMG;
            const size_t idx = (size_t)b * HW + (size_t)gy * WIMG + gx;

            if (MODE == 1) {
                if (in) {
                    union { float4 f4; __half2 h[4]; } u;
                    u.f4 = *(const float4*)(wA + 4 * idx);
                    wv[i][k][0] = u.h[0]; wv[i][k][1] = u.h[1];
                    wv[i][k][2] = u.h[2]; wv[i][k][3] = u.h[3];
                    wcc[i][k] = wC[idx];
                } else {
                    __half2 z = __floats2half2_rn(0.f, 0.f);
                    wv[i][k][0] = z; wv[i][k][1] = z;
                    wv[i][k][2] = z; wv[i][k][3] = z;
                    wcc[i][k] = 0.f;
                }
            } else {
                float wt[8];
                float s = 0.f;
                if (in) {
                    const float* ap = aff + (size_t)b * 8 * HW + (size_t)gy * WIMG + gx;
                    #pragma unroll
                    for (int t = 0; t < 8; ++t) { wt[t] = ap[(size_t)t * HW]; s += fabsf(wt[t]); }
                } else {
                    #pragma unroll
                    for (int t = 0; t < 8; ++t) wt[t] = 0.f;
                    s = 1.f;
                }
                float rr  = in ? 1.0f / s : 0.f;
                float acc = 0.f;
                #pragma unroll
                for (int t = 0; t < 8; ++t) { wt[t] *= rr; acc += wt[t]; }

                union { float4 f4; __half2 h[4]; } u;
                u.h[0] = __floats2half2_rn(wt[0], wt[1]);
                u.h[1] = __floats2half2_rn(wt[2], wt[3]);
                u.h[2] = __floats2half2_rn(wt[4], wt[5]);
                u.h[3] = __floats2half2_rn(wt[6], wt[7]);
                wv[i][k][0] = u.h[0]; wv[i][k][1] = u.h[1];
                wv[i][k][2] = u.h[2]; wv[i][k][3] = u.h[3];
                wcc[i][k] = in ? 1.0f - acc : 0.f;

                if (MODE == 0) {
                    // store interior weights for launch 2 (each image px
                    // interior to exactly one block; rows/cols unique/thread)
                    if ((unsigned)(gy - oy) < (unsigned)TILE &&
                        (unsigned)(gx - ox) < (unsigned)TILE) {
                        *(float4*)(wA + 4 * idx) = u.f4;
                        wC[idx] = wcc[i][k];
                    }
                }
            }
        }
    }
    __syncthreads();

    // ---- 12 fused steps; 6x4 window via float2 LDS reads, all lane-local
    const float* fin = fA;
    float*       fo  = fB;

    #pragma unroll 1
    for (int s = 0; s < TSTEPS; ++s) {
        // wave-uniform liveness: wave w writes staged rows 8w+1..8w+8; ring
        // needed after step s is [s+1, 64-s]
        const bool live = (8 * w + 8 >= s + 1) && (8 * w + 1 <= 64 - s);
        if (live) {
            const float* bp = fin + (4 * rg) * PITCH + 2 * cu;  // staged (4rg, 2cu)
            float2 p0[6], p1[6];
            #pragma unroll
            for (int r = 0; r < 6; ++r) {
                p0[r] = *(const float2*)(bp + r * PITCH);       // cols 2cu,2cu+1
                p1[r] = *(const float2*)(bp + r * PITCH + 2);   // cols 2cu+2,2cu+3
            }
            float Wm[6][4];
            #pragma unroll
            for (int r = 0; r < 6; ++r) {
                Wm[r][0] = p0[r].x; Wm[r][1] = p0[r].y;
                Wm[r][2] = p1[r].x; Wm[r][3] = p1[r].y;
            }
            float* wp = fo + (4 * rg + 1) * PITCH + (2 * cu + 1);
            #pragma unroll
            for (int i = 0; i < 4; ++i) {
                #pragma unroll
                for (int k = 0; k < 2; ++k) {
                    float o = wcc[i][k] * Wm[i + 1][k + 1]
                        + __low2float (wv[i][k][0]) * Wm[i][k]          // NW
                        + __high2float(wv[i][k][0]) * Wm[i][k + 1]      // N
                        + __low2float (wv[i][k][1]) * Wm[i][k + 2]      // NE
                        + __high2float(wv[i][k][1]) * Wm[i + 1][k]      // W
                        + __low2float (wv[i][k][2]) * Wm[i + 1][k + 2]  // E
                        + __high2float(wv[i][k][2]) * Wm[i + 2][k]      // SW
                        + __low2float (wv[i][k][3]) * Wm[i + 2][k + 1]  // S
                        + __high2float(wv[i][k][3]) * Wm[i + 2][k + 2]; // SE
                    wp[i * PITCH + k] = o;
                }
            }
        }
        __syncthreads();
        const float* t = fin; fin = fo; fo = (float*)t;
    }

    // ---- store 40x40 tile (fin == fA after 12 steps)
    for (int i = tid; i < TILE * (TILE / 4); i += NT) {
        int r  = i / (TILE / 4);
        int c4 = (i - r * (TILE / 4)) * 4;
        const float* p = fin + (IH + r) * PITCH + IH + c4;
        float4 v = make_float4(p[0], p[1], p[2], p[3]);
        *(float4*)&db[(size_t)(oy + r) * WIMG + ox + c4] = v;
    }
}

extern "C" void kernel_launch(void* const* d_in, const int* in_sizes, int n_in,
                              void* d_out, int out_size, void* d_ws, size_t ws_size,
                              hipStream_t stream)
{
    const float* aff  = (const float*)d_in[0];
    const float* feat = (const float*)d_in[1];
    float* out = (float*)d_out;

    char* ws = (char*)d_ws;
    float*   wsFrame = (float*)ws;
    __half2* wA      = (__half2*)(ws + WS_FRAME_B);
    float*   wC      = (float*)(ws + WS_FRAME_B + WS_WA_B);

    dim3 blk(NT, 1, 1);
    dim3 grd(WIMG / TILE, HIMG / TILE, BN);   // 16 x 12 x 8 = 1536 blocks

    if (ws_size >= WS_NEED) {
        affprop12<0><<<grd, blk, 0, stream>>>(aff, wA, wC, feat, wsFrame);
        affprop12<1><<<grd, blk, 0, stream>>>(aff, wA, wC, wsFrame, out);
    } else {
        affprop12<2><<<grd, blk, 0, stream>>>(aff, nullptr, nullptr, feat, wsFrame);
        affprop12<2><<<grd, blk, 0, stream>>>(aff, nullptr, nullptr, wsFrame, out);
    }
}

// Round 4
// 218.235 us; speedup vs baseline: 1.0648x; 1.0648x over previous
//
#include <hip/hip_runtime.h>
#include <hip/hip_fp16.h>
#include <cstddef>

// AffinityPropagate: per-pixel normalized 3x3 stencil, 24 steps.
// R9: R6 structure (1 col x 8 rows/thread, batch 10x3 b32 window reads,
// conflict-free stride-1 LDS, dead-wave skip, 12 barriers) with weights
// UNPACKED TO F32 REGISTERS once after load (72 regs). R8 evidence:
// VALUBusy*dur ~= 3.5K insts/wave vs ~1.8K modeled with fma_mix -> compiler
// is NOT fusing half2float*x into v_fma_mix; it re-converts 64 halves per
// thread PER STEP. f32 weight regs make the inner loop 9 pure v_fma_f32 per
// output px. Workspace format stays half2-packed (HBM bytes unchanged);
// launch_bounds (512,3) so +70 VGPR doesn't spill.
// R7 (fewer barriers) and R8 (fewer LDS ops) both regressed -> kernel is
// serial-per-wave bound: VALU insts + LDS latency, ~3 waves/SIMD. Cutting
// per-step VALU is the remaining lever.
//
// Tap order: w0=NW w1=N w2=NE w3=W [center] w4=E w5=SW w6=S w7=SE
//
// Ring/frontier: staged halo 13 (66x66), weight halo 12 (64x64 = staged rows/
// cols 1..64, rewritten every step). Valid staged rings after step s: [s,65-s];
// after 12 steps rows/cols 12..53 valid; output tile is 13..52. Out-of-image
// px have all-zero weights -> stay exactly 0 = zero padding.

#define HIMG 480
#define WIMG 640
#define HW   (HIMG * WIMG)
#define BN   8

#define TILE   40
#define TSTEPS 12
#define IH     13                // staged halo
#define WHL    12                // weight halo
#define SW     66                // staged rows/cols
#define PITCH  68                // LDS row pitch (floats)
#define NT     512

#define WS_FRAME_B  ((size_t)BN * HW * 4)            // 9,830,400
#define WS_WA_B     ((size_t)BN * HW * 16)           // 39,321,600
#define WS_WC_B     ((size_t)BN * HW * 4)            // 9,830,400
#define WS_NEED     (WS_FRAME_B + WS_WA_B + WS_WC_B) // 58,982,400

// MODE: 0 = normalize in-kernel + store interior weights to wA/wC
//       1 = load packed weights from wA/wC
//       2 = normalize in-kernel, no store (fallback when ws too small)
template <int MODE>
__global__ __launch_bounds__(NT, 3) void affprop12(
    const float* __restrict__ aff,
    __half2* __restrict__ wA,
    float* __restrict__ wC,
    const float* __restrict__ src,
    float* __restrict__ dst)
{
    __shared__ float fA[SW * PITCH];
    __shared__ float fB[SW * PITCH];

    const int tid = threadIdx.x;
    const int ox  = blockIdx.x * TILE;
    const int oy  = blockIdx.y * TILE;
    const int b   = blockIdx.z;

    const float* __restrict__ sb = src + (size_t)b * HW;
    float*       __restrict__ db = dst + (size_t)b * HW;

    // ---- stage input region [oy-13, oy+53) x [ox-13, ox+53), 0 outside image
    for (int i = tid; i < SW * SW; i += NT) {
        int r  = i / SW;
        int c  = i - r * SW;
        int gy = oy - IH + r;
        int gx = ox - IH + c;
        float v = 0.f;
        if ((unsigned)gy < (unsigned)HIMG && (unsigned)gx < (unsigned)WIMG)
            v = sb[gy * WIMG + gx];
        fA[r * PITCH + c] = v;
    }
    // ---- zero-fill buffer B (deterministic stale rings)
    for (int i = tid; i < SW * PITCH / 4; i += NT)
        *(float4*)&fB[4 * i] = make_float4(0.f, 0.f, 0.f, 0.f);

    // ---- per-thread: weight column c, row group g (8 rows)
    const int c  = tid & 63;          // weight col 0..63
    const int g  = tid >> 6;          // row group 0..7
    const int sc = c + 1;             // staged col of this thread's outputs

    float ww[8][8];     // [row i][tap 0..7], f32 (the VALU-saving change)
    float wcc[8];       // center weights

    #pragma unroll
    for (int i = 0; i < 8; ++i) {
        const int gy = oy - WHL + 8 * g + i;
        const int gx = ox - WHL + c;
        const bool in = (unsigned)gy < (unsigned)HIMG && (unsigned)gx < (unsigned)WIMG;
        const size_t idx = (size_t)b * HW + (size_t)gy * WIMG + gx;

        if (MODE == 1) {
            if (in) {
                union { float4 f4; __half2 h[4]; } u;
                u.f4 = *(const float4*)(wA + 4 * idx);
                // one-time unpack to f32
                #pragma unroll
                for (int t = 0; t < 4; ++t) {
                    ww[i][2 * t]     = __low2float (u.h[t]);
                    ww[i][2 * t + 1] = __high2float(u.h[t]);
                }
                wcc[i] = wC[idx];
            } else {
                #pragma unroll
                for (int t = 0; t < 8; ++t) ww[i][t] = 0.f;
                wcc[i] = 0.f;
            }
        } else {
            float w[8];
            float s = 0.f;
            if (in) {
                const float* ap = aff + (size_t)b * 8 * HW + (size_t)gy * WIMG + gx;
                #pragma unroll
                for (int k = 0; k < 8; ++k) { w[k] = ap[(size_t)k * HW]; s += fabsf(w[k]); }
            } else {
                #pragma unroll
                for (int k = 0; k < 8; ++k) w[k] = 0.f;
                s = 1.f;
            }
            float rr  = in ? 1.0f / s : 0.f;
            float acc = 0.f;
            #pragma unroll
            for (int k = 0; k < 8; ++k) { w[k] *= rr; acc += w[k]; }

            #pragma unroll
            for (int k = 0; k < 8; ++k) ww[i][k] = w[k];
            wcc[i] = in ? 1.0f - acc : 0.f;

            if (MODE == 0) {
                // store interior weights for launch 2 (each image px interior
                // to exactly one block); pack to half2 for storage only
                if ((unsigned)(gy - oy) < (unsigned)TILE &&
                    (unsigned)(gx - ox) < (unsigned)TILE) {
                    union { float4 f4; __half2 h[4]; } u;
                    u.h[0] = __floats2half2_rn(w[0], w[1]);
                    u.h[1] = __floats2half2_rn(w[2], w[3]);
                    u.h[2] = __floats2half2_rn(w[4], w[5]);
                    u.h[3] = __floats2half2_rn(w[6], w[7]);
                    *(float4*)(wA + 4 * idx) = u.f4;
                    wC[idx] = wcc[i];
                }
            }
        }
    }
    __syncthreads();

    // ---- 12 fused steps; whole 10x3 window batch-read into registers,
    //      then 8 outputs (9 pure v_fma_f32 each), then 8 writes.
    const float* fin = fA;
    float*       fo  = fB;

    #pragma unroll 1
    for (int s = 0; s < TSTEPS; ++s) {
        // wave-uniform liveness: wave g writes staged rows 8g+1..8g+8; the
        // ring needed after step s is [s+1, 64-s].
        const bool live = (8 * g + 8 >= s + 1) && (8 * g + 1 <= 64 - s);
        if (live) {
            const float* bp = fin + (8 * g) * PITCH + c;   // staged cols sc-1..sc+1
            float t0[10], t1[10], t2[10];
            #pragma unroll
            for (int r = 0; r < 10; ++r) {
                t0[r] = bp[r * PITCH + 0];
                t1[r] = bp[r * PITCH + 1];
                t2[r] = bp[r * PITCH + 2];
            }
            float* wp = fo + (8 * g + 1) * PITCH + sc;
            #pragma unroll
            for (int i = 0; i < 8; ++i) {
                float o = wcc[i]   * t1[i + 1]
                        + ww[i][0] * t0[i]        // NW
                        + ww[i][1] * t1[i]        // N
                        + ww[i][2] * t2[i]        // NE
                        + ww[i][3] * t0[i + 1]    // W
                        + ww[i][4] * t2[i + 1]    // E
                        + ww[i][5] * t0[i + 2]    // SW
                        + ww[i][6] * t1[i + 2]    // S
                        + ww[i][7] * t2[i + 2];   // SE
                wp[i * PITCH] = o;
            }
        }
        __syncthreads();
        const float* t = fin; fin = fo; fo = (float*)t;
    }

    // ---- store 40x40 tile (fin == fA after 12 steps)
    for (int i = tid; i < TILE * (TILE / 4); i += NT) {
        int r  = i / (TILE / 4);
        int c4 = (i - r * (TILE / 4)) * 4;
        const float* p = fin + (IH + r) * PITCH + IH + c4;
        float4 v = make_float4(p[0], p[1], p[2], p[3]);
        *(float4*)&db[(size_t)(oy + r) * WIMG + ox + c4] = v;
    }
}

extern "C" void kernel_launch(void* const* d_in, const int* in_sizes, int n_in,
                              void* d_out, int out_size, void* d_ws, size_t ws_size,
                              hipStream_t stream)
{
    const float* aff  = (const float*)d_in[0];
    const float* feat = (const float*)d_in[1];
    float* out = (float*)d_out;

    char* ws = (char*)d_ws;
    float*   wsFrame = (float*)ws;
    __half2* wA      = (__half2*)(ws + WS_FRAME_B);
    float*   wC      = (float*)(ws + WS_FRAME_B + WS_WA_B);

    dim3 blk(NT, 1, 1);
    dim3 grd(WIMG / TILE, HIMG / TILE, BN);   // 16 x 12 x 8 = 1536 blocks

    if (ws_size >= WS_NEED) {
        affprop12<0><<<grd, blk, 0, stream>>>(aff, wA, wC, feat, wsFrame);
        affprop12<1><<<grd, blk, 0, stream>>>(aff, wA, wC, wsFrame, out);
    } else {
        affprop12<2><<<grd, blk, 0, stream>>>(aff, nullptr, nullptr, feat, wsFrame);
        affprop12<2><<<grd, blk, 0, stream>>>(aff, nullptr, nullptr, wsFrame, out);
    }
}